// Round 4
// baseline (549.148 us; speedup 1.0000x reference)
//
#include <hip/hip_runtime.h>
#include <hip/hip_bf16.h>

// GQA flash attention fwd, causal + sliding window 1024.
// B=2, S=2048, Hq=32, Hkv=8 (group 4), D=128.
// Inputs/outputs are FP32 (per reference setup_inputs); compute path converts
// to bf16 in registers for MFMA, accumulates fp32. No +-INFINITY anywhere
// (finite sentinels only — safe under -ffast-math).

#define H_Q 32
#define H_KV 8
#define HDIM 128
#define SEQLEN 2048
#define NBATCH 2
#define WIN 1024
#define QK_SCALE 0.08838834764831845f
#define LOG2E 1.4426950408889634f
#define SCALE_LOG2E (QK_SCALE * LOG2E)

#define NEG_BIG  (-3.0e38f)   // finite "masked" sentinel
#define NEG_CLMP (-1.0e30f)   // exponent-reference clamp: exp2(NEG_BIG-NEG_CLMP)==0

#define QPITCH (H_Q * HDIM)   // 4096 floats
#define KPITCH (H_KV * HDIM)  // 1024 floats

typedef __attribute__((ext_vector_type(8))) short  short8;   // 8 bf16 = 4 VGPR
typedef __attribute__((ext_vector_type(4))) short  short4v;  // 4 bf16 = 8 B
typedef __attribute__((ext_vector_type(4))) float  floatx4;

static __device__ __forceinline__ short bf16bits(float x) {
    return __builtin_bit_cast(short, __float2bfloat16(x));
}

__global__ __launch_bounds__(256, 2)
void fa_fwd(const float* __restrict__ Q,
            const float* __restrict__ K,
            const float* __restrict__ V,
            float* __restrict__ O)
{
    // pitches in shorts; multiples of 4 keep 8B alignment for short4 stores
    __shared__ __align__(16) short lds_k[64][136];   // K tile  [key][d]  (bf16)
    __shared__ __align__(16) short lds_vt[128][72];  // V tile transposed [d][key]
    __shared__ __align__(16) short lds_p[4][16][72]; // per-wave P [q][key]

    const int bi  = blockIdx.x;
    const int qt  = bi & 31;          // 32 q-tiles of 64
    const int h   = (bi >> 5) & 31;
    const int b   = bi >> 10;
    const int kvh = h >> 2;           // GQA group of 4
    const int q0  = qt << 6;

    const int tid  = threadIdx.x;
    const int wid  = tid >> 6;        // wave id 0..3, owns rows q0+wid*16..+15
    const int lane = tid & 63;
    const int ln16 = lane & 15;
    const int lg   = lane >> 4;       // lane group 0..3

    const float* Qb = Q + (size_t)b * SEQLEN * QPITCH + (size_t)h * HDIM;
    const float* Kb = K + (size_t)b * SEQLEN * KPITCH + (size_t)kvh * HDIM;
    const float* Vb = V + (size_t)b * SEQLEN * KPITCH + (size_t)kvh * HDIM;
    float*       Ob = O + (size_t)b * SEQLEN * QPITCH + (size_t)h * HDIM;

    // ---- Q fragments (A operand), held in registers for the whole kernel.
    // A layout: m = ln16 (query row), k = lg*8 + j within each 32-wide k-step.
    short8 qf[4];
    {
        const int qrow = q0 + wid * 16 + ln16;
        const float* qs = Qb + (size_t)qrow * QPITCH + lg * 8;
        #pragma unroll
        for (int kk = 0; kk < 4; ++kk) {
            floatx4 a = *(const floatx4*)(qs + kk * 32);
            floatx4 c = *(const floatx4*)(qs + kk * 32 + 4);
            short8 f;
            #pragma unroll
            for (int j = 0; j < 4; ++j) { f[j] = bf16bits(a[j]); f[4 + j] = bf16bits(c[j]); }
            qf[kk] = f;
        }
    }

    floatx4 oacc[8];                  // O accum, C layout: col=d (ln16), row=lg*4+r
    #pragma unroll
    for (int i = 0; i < 8; ++i) oacc[i] = (floatx4){0.f, 0.f, 0.f, 0.f};
    float m_r[4], l_r[4];             // online-softmax state for rows lg*4+r
    #pragma unroll
    for (int r = 0; r < 4; ++r) { m_r[r] = NEG_BIG; l_r[r] = 0.f; }

    int kvlo = q0 - (WIN - 1);
    if (kvlo < 0) kvlo = 0;
    kvlo &= ~63;

    for (int kk0 = kvlo; kk0 <= q0; kk0 += 64) {
        __syncthreads();              // previous tile's LDS reads done
        // ---- stage K [64][128] and V^T [128][64] into LDS, converting to bf16.
        // flat float4 index fi = i*256 + tid: lane-consecutive addresses.
        #pragma unroll
        for (int i = 0; i < 8; ++i) {
            const int fi  = i * 256 + tid;     // 0..2047
            const int key = fi >> 5;           // 0..63
            const int c4  = (fi & 31) * 4;     // float col 0,4,...,124
            const size_t grow = (size_t)(kk0 + key) * KPITCH + c4;
            floatx4 kv = *(const floatx4*)(Kb + grow);
            short4v ks;
            #pragma unroll
            for (int j = 0; j < 4; ++j) ks[j] = bf16bits(kv[j]);
            *(short4v*)&lds_k[key][c4] = ks;
            floatx4 vv = *(const floatx4*)(Vb + grow);
            #pragma unroll
            for (int j = 0; j < 4; ++j)
                lds_vt[c4 + j][key] = bf16bits(vv[j]);   // transpose on the way in
        }
        __syncthreads();

        // ---- S = Q K^T  (16 MFMAs per wave)
        float sc[4][4];
        #pragma unroll
        for (int nt = 0; nt < 4; ++nt) {
            floatx4 acc = (floatx4){0.f, 0.f, 0.f, 0.f};
            #pragma unroll
            for (int kk = 0; kk < 4; ++kk) {
                short8 kf = *(const short8*)&lds_k[nt * 16 + ln16][kk * 32 + lg * 8];
                acc = __builtin_amdgcn_mfma_f32_16x16x32_bf16(qf[kk], kf, acc, 0, 0, 0);
            }
            #pragma unroll
            for (int r = 0; r < 4; ++r) sc[nt][r] = acc[r];
        }

        // ---- scale + mask (interior tiles skip the mask ALU entirely)
        const bool full = (kk0 + 63 <= q0) && (kk0 >= q0 - 960);
        float pm[4];
        #pragma unroll
        for (int r = 0; r < 4; ++r) pm[r] = NEG_BIG;
        if (full) {
            #pragma unroll
            for (int nt = 0; nt < 4; ++nt)
                #pragma unroll
                for (int r = 0; r < 4; ++r) {
                    sc[nt][r] *= SCALE_LOG2E;
                    pm[r] = fmaxf(pm[r], sc[nt][r]);
                }
        } else {
            #pragma unroll
            for (int nt = 0; nt < 4; ++nt) {
                const int kcol = kk0 + nt * 16 + ln16;
                #pragma unroll
                for (int r = 0; r < 4; ++r) {
                    const int qrow = q0 + wid * 16 + lg * 4 + r;
                    const bool ok = (kcol <= qrow) && (qrow - kcol < WIN);
                    sc[nt][r] = ok ? sc[nt][r] * SCALE_LOG2E : NEG_BIG;
                    pm[r] = fmaxf(pm[r], sc[nt][r]);
                }
            }
        }
        // row-reduce max across the 16 lanes holding each row
        #pragma unroll
        for (int r = 0; r < 4; ++r)
            #pragma unroll
            for (int off = 1; off < 16; off <<= 1)
                pm[r] = fmaxf(pm[r], __shfl_xor(pm[r], off, 16));

        float alpha[4], mne[4];
        #pragma unroll
        for (int r = 0; r < 4; ++r) {
            const float mn = fmaxf(m_r[r], pm[r]);        // finite always
            const float me = fmaxf(mn, NEG_CLMP);         // exponent reference
            alpha[r] = exp2f(m_r[r] - me);                // NEG_BIG-NEG_CLMP -> 0
            m_r[r] = mn;
            mne[r] = me;
        }

        // ---- P = exp2(s - m), write to wave-private LDS in [q][key] layout
        float psum[4] = {0.f, 0.f, 0.f, 0.f};
        #pragma unroll
        for (int nt = 0; nt < 4; ++nt)
            #pragma unroll
            for (int r = 0; r < 4; ++r) {
                const float p = exp2f(sc[nt][r] - mne[r]);  // masked -> exact 0
                psum[r] += p;
                lds_p[wid][lg * 4 + r][nt * 16 + ln16] = bf16bits(p);
            }
        #pragma unroll
        for (int r = 0; r < 4; ++r) {
            #pragma unroll
            for (int off = 1; off < 16; off <<= 1)
                psum[r] += __shfl_xor(psum[r], off, 16);
            l_r[r] = l_r[r] * alpha[r] + psum[r];
        }
        #pragma unroll
        for (int dt = 0; dt < 8; ++dt)
            #pragma unroll
            for (int r = 0; r < 4; ++r) oacc[dt][r] *= alpha[r];

        // Fence between scalar P-writes and vector P-reads (cross-lane dep
        // through LDS; barrier = compiler-opaque shared-memory fence).
        __syncthreads();

        // ---- O += P V  (16 MFMAs per wave)
        #pragma unroll
        for (int ks = 0; ks < 2; ++ks) {
            short8 pf = *(const short8*)&lds_p[wid][ln16][ks * 32 + lg * 8];
            #pragma unroll
            for (int dt = 0; dt < 8; ++dt) {
                short8 vf = *(const short8*)&lds_vt[dt * 16 + ln16][ks * 32 + lg * 8];
                oacc[dt] = __builtin_amdgcn_mfma_f32_16x16x32_bf16(pf, vf, oacc[dt], 0, 0, 0);
            }
        }
    }

    // ---- epilogue: normalize and store fp32
    #pragma unroll
    for (int r = 0; r < 4; ++r) {
        const float inv = 1.0f / l_r[r];   // diagonal key always valid -> l_r>0
        const int qrow = q0 + wid * 16 + lg * 4 + r;
        float* dst = Ob + (size_t)qrow * QPITCH;
        #pragma unroll
        for (int dt = 0; dt < 8; ++dt)
            dst[dt * 16 + ln16] = oacc[dt][r] * inv;
    }
}

extern "C" void kernel_launch(void* const* d_in, const int* in_sizes, int n_in,
                              void* d_out, int out_size, void* d_ws, size_t ws_size,
                              hipStream_t stream) {
    const float* Q = (const float*)d_in[0];
    const float* K = (const float*)d_in[1];
    const float* V = (const float*)d_in[2];
    float* O = (float*)d_out;
    dim3 grid(NBATCH * H_Q * (SEQLEN / 64));   // 2048 blocks: (b, h, qtile)
    fa_fwd<<<grid, 256, 0, stream>>>(Q, K, V, O);
}